// Round 2
// baseline (453.984 us; speedup 1.0000x reference)
//
#include <hip/hip_runtime.h>
#include <stdint.h>

#define Nn 8192
#define Dd 1024
#define Cc_ 1000

typedef __bf16 bf16x8 __attribute__((ext_vector_type(8)));
typedef float f32x4 __attribute__((ext_vector_type(4)));
typedef int i32x4 __attribute__((ext_vector_type(4)));
typedef int i32x8 __attribute__((ext_vector_type(8)));
typedef const __attribute__((address_space(1))) void* gas1_t;
typedef __attribute__((address_space(3))) void* las3_t;

__device__ __forceinline__ unsigned short f2bf(float f) {
  unsigned u = __float_as_uint(f);
  u = (u + 0x7fffu + ((u >> 16) & 1u)) >> 16;  // RNE
  return (unsigned short)u;
}
__device__ __forceinline__ float bf2f(unsigned short h) {
  return __uint_as_float(((unsigned)h) << 16);
}
__device__ __forceinline__ unsigned char f2fp8(float v) {
  int p = __builtin_amdgcn_cvt_pk_fp8_f32(v, v, 0, false);  // OCP e4m3 on gfx950
  return (unsigned char)(p & 0xff);
}
__device__ __forceinline__ void cp16(const void* g, void* l) {
  __builtin_amdgcn_global_load_lds((gas1_t)g, (las3_t)l, 16, 0, 0);
}
__device__ __forceinline__ float wred_sum(float v) {
#pragma unroll
  for (int m = 32; m; m >>= 1) v += __shfl_xor(v, m, 64);
  return v;
}

// ---------------------------------------------------------------------------
// 256x256-tile, BK=128, 8-wave pipelined MX-fp8 GEMM (T3+T4+T5 schedule).
// C = alpha*(A[M][K] @ Bt[*][K]^T) variants:
//   MODE 0: fp32 atomicAdd into Cout (split-K via gridDim.z; Cout pre-zeroed)
//   MODE 1: fp8 out + per-col bias
//   MODE 2: fp8 out, exp(alpha*acc), fused row-sum into lsum
// LDS 160 KiB: A triple-buffered (3x32KB slots, tile t -> slot t%3),
//              B double-buffered (2x32KB at +98304, tile t -> slot t&1).
// Per K-tile, 4 phases (quadrants of the wave's 128x64 output, 8 MFMA each):
//   p0: read a0[4]+b0[2]; stage B(t+1).c0   p1: read b1[2]; stage B(t+1).c1
//   p2: read a1[4];       stage A(t+2).c0   p3: (no reads); stage A(t+2).c1
// Boundary wait per tile: s_waitcnt vmcnt(4) -- leaves A(t+2)'s 4 loads in
// flight, guarantees A(t+1)/B(t+1) arrived (FIFO vmcnt). vmcnt(0) only at the
// tail (t+2 >= nt, where A(t+2) isn't issued and vmcnt(4) would NOT cover
// B(t+1) -- round-1 bug #2).
// Overwrite safety: every stage lands >=3 barrier-separated phases after the
// last ds_read of the slot it overwrites (A: 5 phases, B: 3 phases).
// STAGING (round-1 bug #1 fixed): global_load_lds LDS dest must be
// WAVE-UNIFORM (HW writes lane i at base+i*16, m104/m108). Each wave stages
// whole 1-KiB chunks c = wave*2+s (s=0,1) per 16-KiB half-tile cc: LDS base
// slot*32768 + cc*16384 + c*1024 (uniform); per-LANE global address carries
// the verified bijection: row = cc*128 + 8c + (lane>>3),
// h = ((lane>>2)^(lane>>3))&1, u2 = (lane&3)^((lane>>4)&3).
// Frag read decode (verified): byte = r*128 + 64*((q>>1)^(r&1)) +
// 16*((((q&1)<<1))^((r>>1)&3)), hi = lo^16.
// Requires M%256==0, Nout%256==0, K%128==0, nt>=2 (all call sites satisfy).
// ---------------------------------------------------------------------------
template <int MODE>
__global__ __launch_bounds__(512, 2) void gemm_mx8(
    const unsigned char* __restrict__ A,
    const unsigned char* __restrict__ Bt,
    const float* __restrict__ bias,
    void* __restrict__ Cout,
    int K, int Nout, int lda, int ldb, float alpha,
    float* __restrict__ lsum) {
  __shared__ __attribute__((aligned(16))) unsigned char lds[163840];

  const int tid = threadIdx.x;
  const int lane = tid & 63;
  const int wave = tid >> 6;
  const int wr = (wave >> 2) << 7;   // 0 / 128
  const int wc = (wave & 3) << 6;    // 0,64,128,192
  const long row0 = (long)blockIdx.x << 8;
  const long col0 = (long)blockIdx.y << 8;
  A += (long)blockIdx.z * K;         // split-K slice (z=0 when gridDim.z==1)
  Bt += (long)blockIdx.z * K;

  // staging: wave-uniform LDS chunk bases, per-lane global decode (see header)
  const int r_ = lane >> 3;
  const int go = ((((lane >> 2) ^ (lane >> 3)) & 1) << 6) +
                 (((lane & 3) ^ ((lane >> 4) & 3)) << 4);
  long gAo[2], gBo[2];
  int lofs[2];
#pragma unroll
  for (int s = 0; s < 2; ++s) {
    const int c = (wave << 1) + s;
    gAo[s] = (row0 + (c << 3) + r_) * (long)lda + go;
    gBo[s] = (col0 + (c << 3) + r_) * (long)ldb + go;
    lofs[s] = c << 10;
  }
  const long ldaC = (long)lda << 7;  // 128-row (cc) stride
  const long ldbC = (long)ldb << 7;

  auto stA = [&](int slot, int cc, int kk) {
#pragma unroll
    for (int s = 0; s < 2; ++s)
      cp16(A + gAo[s] + cc * ldaC + kk,
           &lds[slot * 32768 + cc * 16384 + lofs[s]]);
  };
  auto stB = [&](int slot, int cc, int kk) {
#pragma unroll
    for (int s = 0; s < 2; ++s)
      cp16(Bt + gBo[s] + cc * ldbC + kk,
           &lds[98304 + slot * 32768 + cc * 16384 + lofs[s]]);
  };

  // frag read decode (verified layout)
  const int m_ = lane & 15;
  const int q_ = lane >> 4;
  const int sw = ((((q_ >> 1) ^ m_) & 1) << 6) +
                 (((((q_ & 1) << 1) ^ ((m_ >> 1) & 3))) << 4);
  const int foA = ((wr + m_) << 7) + sw;
  const int foB = ((wc + m_) << 7) + sw;
  auto rdA = [&](int ab, int i) {
    const int ba = ab + foA + (i << 11);
    i32x4 lo = *(const i32x4*)&lds[ba];
    i32x4 hi = *(const i32x4*)&lds[ba ^ 16];
    return __builtin_shufflevector(lo, hi, 0, 1, 2, 3, 4, 5, 6, 7);
  };
  auto rdB = [&](int bb, int j) {
    const int ba = bb + foB + (j << 11);
    i32x4 lo = *(const i32x4*)&lds[ba];
    i32x4 hi = *(const i32x4*)&lds[ba ^ 16];
    return __builtin_shufflevector(lo, hi, 0, 1, 2, 3, 4, 5, 6, 7);
  };

  f32x4 acc[8][4] = {};
  const int nt = K >> 7;

  // prologue: A(0) both chunks, B(0) both chunks, A(1) both chunks (12 loads)
  stA(0, 0, 0); stA(0, 1, 0);
  stB(0, 0, 0); stB(0, 1, 0);
  if (nt > 1) {
    stA(1, 0, 128); stA(1, 1, 128);
    asm volatile("s_waitcnt vmcnt(4)" ::: "memory");  // A(0),B(0) arrived
  } else {
    asm volatile("s_waitcnt vmcnt(0)" ::: "memory");
  }
  __builtin_amdgcn_s_barrier();

  int sa = 0;  // A slot of tile t (= t % 3)
  for (int t = 0; t < nt; ++t) {
    const int sb = t & 1;
    const int sa2 = sa >= 1 ? sa - 1 : 2;  // (t+2) % 3
    const int aB = sa * 32768;
    const int bB = 98304 + sb * 32768;
    i32x8 a0[4], a1[4], b0[2], b1[2];

    // ---- phase 0: q(0,0) ----
#pragma unroll
    for (int i = 0; i < 4; ++i) a0[i] = rdA(aB, i);
#pragma unroll
    for (int j = 0; j < 2; ++j) b0[j] = rdB(bB, j);
    if (t + 1 < nt) stB(sb ^ 1, 0, (t + 1) << 7);
    __builtin_amdgcn_s_barrier();
    asm volatile("s_waitcnt lgkmcnt(0)" ::: "memory");
    __builtin_amdgcn_sched_barrier(0);
    __builtin_amdgcn_s_setprio(1);
#pragma unroll
    for (int i = 0; i < 4; ++i)
#pragma unroll
      for (int j = 0; j < 2; ++j)
        acc[i][j] = __builtin_amdgcn_mfma_scale_f32_16x16x128_f8f6f4(
            a0[i], b0[j], acc[i][j], 0, 0, 0, 0x7f7f7f7f, 0, 0x7f7f7f7f);
    __builtin_amdgcn_s_setprio(0);
    __builtin_amdgcn_s_barrier();

    // ---- phase 1: q(0,1) ----
#pragma unroll
    for (int j = 0; j < 2; ++j) b1[j] = rdB(bB, 2 + j);
    if (t + 1 < nt) stB(sb ^ 1, 1, (t + 1) << 7);
    __builtin_amdgcn_s_barrier();
    asm volatile("s_waitcnt lgkmcnt(0)" ::: "memory");
    __builtin_amdgcn_sched_barrier(0);
    __builtin_amdgcn_s_setprio(1);
#pragma unroll
    for (int i = 0; i < 4; ++i)
#pragma unroll
      for (int j = 0; j < 2; ++j)
        acc[i][2 + j] = __builtin_amdgcn_mfma_scale_f32_16x16x128_f8f6f4(
            a0[i], b1[j], acc[i][2 + j], 0, 0, 0, 0x7f7f7f7f, 0, 0x7f7f7f7f);
    __builtin_amdgcn_s_setprio(0);
    __builtin_amdgcn_s_barrier();

    // ---- phase 2: q(1,0) ----
#pragma unroll
    for (int i = 0; i < 4; ++i) a1[i] = rdA(aB, 4 + i);
    if (t + 2 < nt) stA(sa2, 0, (t + 2) << 7);
    __builtin_amdgcn_s_barrier();
    asm volatile("s_waitcnt lgkmcnt(0)" ::: "memory");
    __builtin_amdgcn_sched_barrier(0);
    __builtin_amdgcn_s_setprio(1);
#pragma unroll
    for (int i = 0; i < 4; ++i)
#pragma unroll
      for (int j = 0; j < 2; ++j)
        acc[4 + i][j] = __builtin_amdgcn_mfma_scale_f32_16x16x128_f8f6f4(
            a1[i], b0[j], acc[4 + i][j], 0, 0, 0, 0x7f7f7f7f, 0, 0x7f7f7f7f);
    __builtin_amdgcn_s_setprio(0);
    __builtin_amdgcn_s_barrier();

    // ---- phase 3: q(1,1) + counted boundary wait ----
    if (t + 2 < nt) stA(sa2, 1, (t + 2) << 7);
    __builtin_amdgcn_s_setprio(1);
#pragma unroll
    for (int i = 0; i < 4; ++i)
#pragma unroll
      for (int j = 0; j < 2; ++j)
        acc[4 + i][2 + j] = __builtin_amdgcn_mfma_scale_f32_16x16x128_f8f6f4(
            a1[i], b1[j], acc[4 + i][2 + j], 0, 0, 0, 0x7f7f7f7f, 0,
            0x7f7f7f7f);
    __builtin_amdgcn_s_setprio(0);
    if (t + 2 < nt)  // steady state: A(t+2)'s 4 loads may stay in flight
      asm volatile("s_waitcnt vmcnt(4)" ::: "memory");
    else             // tail: must fully cover B(t+1) (A(t+2) not issued)
      asm volatile("s_waitcnt vmcnt(0)" ::: "memory");
    __builtin_amdgcn_s_barrier();
    sa = sa == 2 ? 0 : sa + 1;
  }

  // C/D layout: col = lane&15, row = (lane>>4)*4 + reg   [m89-verified]
  const int cr = (lane >> 4) << 2;
  const int ccol = lane & 15;
  if (MODE == 2) {
#pragma unroll
    for (int i = 0; i < 8; ++i) {
      float rs[4] = {0.f, 0.f, 0.f, 0.f};
      const long rowb = row0 + wr + (i << 4) + cr;
#pragma unroll
      for (int j = 0; j < 4; ++j) {
        const long col = col0 + wc + (j << 4) + ccol;
#pragma unroll
        for (int r = 0; r < 4; ++r) {
          float v = __expf(acc[i][j][r] * alpha);
          rs[r] += v;
          ((unsigned char*)Cout)[(rowb + r) * (long)Nout + col] = f2fp8(v);
        }
      }
#pragma unroll
      for (int r = 0; r < 4; ++r) {
        float sv = rs[r];
#pragma unroll
        for (int m2 = 1; m2 < 16; m2 <<= 1) sv += __shfl_xor(sv, m2, 64);
        if (ccol == 0) atomicAdd(&lsum[rowb + r], sv);
      }
    }
  } else if (MODE == 1) {
#pragma unroll
    for (int j = 0; j < 4; ++j) {
      const long col = col0 + wc + (j << 4) + ccol;
      const float bvc = bias ? bias[col] : 0.f;
#pragma unroll
      for (int i = 0; i < 8; ++i) {
        const long rowb = row0 + wr + (i << 4) + cr;
#pragma unroll
        for (int r = 0; r < 4; ++r) {
          float v = acc[i][j][r] * alpha + bvc;
          ((unsigned char*)Cout)[(rowb + r) * (long)Nout + col] = f2fp8(v);
        }
      }
    }
  } else {  // MODE 0: fp32 atomic accumulate (split-K)
#pragma unroll
    for (int j = 0; j < 4; ++j) {
      const long col = col0 + wc + (j << 4) + ccol;
#pragma unroll
      for (int i = 0; i < 8; ++i) {
        const long rowb = row0 + wr + (i << 4) + cr;
#pragma unroll
        for (int r = 0; r < 4; ++r)
          atomicAdd(&((float*)Cout)[(rowb + r) * (long)Nout + col],
                    acc[i][j][r] * alpha);
      }
    }
  }
}

// ---------------------------------------------------------------------------
// Old 128x128 MX-fp8 GEMM (kept for v^T, whose 128-block 256-tile grid would
// half-idle the GPU). Same verified LDS swizzle as gemm_mx8.
// ---------------------------------------------------------------------------
template <int OFP8, int ER, int BROW>
__global__ __launch_bounds__(256, 3) void gemm_mx(
    const unsigned char* __restrict__ A,
    const unsigned char* __restrict__ Bt,
    const float* __restrict__ bias,
    void* __restrict__ Cout,
    int K, int Nout, int lda, int ldb, float alpha,
    float* __restrict__ lsum) {
  __shared__ __attribute__((aligned(16))) unsigned char sA[16384];
  __shared__ __attribute__((aligned(16))) unsigned char sB[16384];

  const int tid = threadIdx.x;
  const int lane = tid & 63;
  const int wave = tid >> 6;
  const int wr = (wave >> 1) << 6;
  const int wc = (wave & 1) << 6;
  const long row0 = (long)blockIdx.x << 7;
  const long col0 = (long)blockIdx.y << 7;

  const unsigned char* gA[4];
  const unsigned char* gB[4];
  unsigned char* lA[4];
  unsigned char* lB[4];
  {
    const int r_ = (lane >> 3);
    const int go = ((((lane >> 2) ^ (lane >> 3)) & 1) << 6) +
                   (((lane & 3) ^ ((lane >> 4) & 3)) << 4);
#pragma unroll
    for (int s = 0; s < 4; ++s) {
      const int c = (wave << 2) + s;
      gA[s] = A + (row0 + (c << 3) + r_) * (long)lda + go;
      gB[s] = Bt + (col0 + (c << 3) + r_) * (long)ldb + go;
      lA[s] = &sA[c << 10];
      lB[s] = &sB[c << 10];
    }
  }

  f32x4 acc[4][4] = {};

  const int m_ = lane & 15;
  const int q_ = lane >> 4;
  const int aoffA = ((wr + m_) << 7) + ((((q_ >> 1) ^ m_) & 1) << 6) +
                    (((((q_ & 1) << 1) ^ ((m_ >> 1) & 3))) << 4);
  const int aoffB = ((wc + m_) << 7) + ((((q_ >> 1) ^ m_) & 1) << 6) +
                    (((((q_ & 1) << 1) ^ ((m_ >> 1) & 3))) << 4);

  for (int k0 = 0; k0 < K; k0 += 128) {
    __syncthreads();
#pragma unroll
    for (int s = 0; s < 4; ++s) {
      cp16(gA[s], lA[s]);
      cp16(gB[s], lB[s]);
      gA[s] += 128;
      gB[s] += 128;
    }
    __syncthreads();

    i32x8 af[4], bfr[4];
#pragma unroll
    for (int i = 0; i < 4; ++i) {
      const int ba = aoffA + (i << 11);
      i32x4 lo = *(const i32x4*)&sA[ba];
      i32x4 hi = *(const i32x4*)&sA[ba ^ 16];
      af[i] = __builtin_shufflevector(lo, hi, 0, 1, 2, 3, 4, 5, 6, 7);
    }
#pragma unroll
    for (int j = 0; j < 4; ++j) {
      const int bb = aoffB + (j << 11);
      i32x4 lo = *(const i32x4*)&sB[bb];
      i32x4 hi = *(const i32x4*)&sB[bb ^ 16];
      bfr[j] = __builtin_shufflevector(lo, hi, 0, 1, 2, 3, 4, 5, 6, 7);
    }
#pragma unroll
    for (int i = 0; i < 4; ++i)
#pragma unroll
      for (int j = 0; j < 4; ++j)
        acc[i][j] = __builtin_amdgcn_mfma_scale_f32_16x16x128_f8f6f4(
            af[i], bfr[j], acc[i][j], 0, 0, 0, 0x7f7f7f7f, 0, 0x7f7f7f7f);
  }

  const int cr = (lane >> 4) << 2;
  const int ccol = lane & 15;
  if (ER) {
    float rs[4][4];
#pragma unroll
    for (int i = 0; i < 4; ++i)
#pragma unroll
      for (int r = 0; r < 4; ++r) rs[i][r] = 0.f;
#pragma unroll
    for (int j = 0; j < 4; ++j) {
      const long col = col0 + wc + (j << 4) + ccol;
#pragma unroll
      for (int i = 0; i < 4; ++i) {
        const long rowb = row0 + wr + (i << 4) + cr;
#pragma unroll
        for (int r = 0; r < 4; ++r) {
          float v = __expf(acc[i][j][r] * alpha);
          rs[i][r] += v;
          ((unsigned char*)Cout)[(rowb + r) * (long)Nout + col] = f2fp8(v);
        }
      }
    }
#pragma unroll
    for (int i = 0; i < 4; ++i)
#pragma unroll
      for (int r = 0; r < 4; ++r) {
        float s = rs[i][r];
#pragma unroll
        for (int m = 1; m < 16; m <<= 1) s += __shfl_xor(s, m, 64);
        if (ccol == 0)
          atomicAdd(&lsum[row0 + wr + (i << 4) + cr + r], s);
      }
  } else {
#pragma unroll
    for (int j = 0; j < 4; ++j) {
      const long col = col0 + wc + (j << 4) + ccol;
      if (col < Nout) {
        float bvc = 0.f;
        if (!BROW && bias) bvc = bias[col];
#pragma unroll
        for (int i = 0; i < 4; ++i) {
          const long rowb = row0 + wr + (i << 4) + cr;
#pragma unroll
          for (int r = 0; r < 4; ++r) {
            float v = acc[i][j][r] * alpha + bvc;
            if (BROW) v += bias[rowb + r];
            const long idx = (rowb + r) * (long)Nout + col;
            if (OFP8)
              ((unsigned char*)Cout)[idx] = f2fp8(v);
            else
              ((float*)Cout)[idx] = v;
          }
        }
      }
    }
  }
}

// ---------------------------------------------------------------------------
// bf16 GEMM (x_r projection and final FC): round-3's verified kernel.
// ---------------------------------------------------------------------------
template <int OBF16>
__global__ __launch_bounds__(256, 4) void gemm_bt(
    const unsigned short* __restrict__ A,
    const unsigned short* __restrict__ Bt,
    const float* __restrict__ bias,
    void* __restrict__ Cout,
    int K, int Nout, int lda, int ldb, float alpha) {
  __shared__ __attribute__((aligned(16))) unsigned short sA[8192];
  __shared__ __attribute__((aligned(16))) unsigned short sB[8192];

  const int tid = threadIdx.x;
  const int lane = tid & 63;
  const int wave = tid >> 6;
  const int wr = (wave >> 1) << 6;
  const int wc = (wave & 1) << 6;
  const long row0 = (long)blockIdx.x << 7;
  const long col0 = (long)blockIdx.y << 7;

  const int srow = (wave << 4) + (lane >> 2);
  const int sq = (lane & 3) ^ ((lane >> 3) & 3);
  const unsigned short* ga1 = A + (row0 + srow) * lda + sq * 8;
  const unsigned short* ga2 = ga1 + (long)64 * lda;
  const unsigned short* gb1 = Bt + (col0 + srow) * ldb + sq * 8;
  const unsigned short* gb2 = gb1 + (long)64 * ldb;
  unsigned short* la1 = &sA[wave * 512];
  unsigned short* la2 = &sA[2048 + wave * 512];
  unsigned short* lb1 = &sB[wave * 512];
  unsigned short* lb2 = &sB[2048 + wave * 512];

  f32x4 acc[4][4] = {};

  const int fq = ((lane >> 4) ^ ((lane >> 1) & 3)) << 3;
  const int am = wr + (lane & 15);
  const int bn = wc + (lane & 15);

  for (int k0 = 0; k0 < K; k0 += 64) {
    __syncthreads();
    cp16(ga1, la1);             cp16(ga2, la2);
    cp16(ga1 + 32, la1 + 4096); cp16(ga2 + 32, la2 + 4096);
    cp16(gb1, lb1);             cp16(gb2, lb2);
    cp16(gb1 + 32, lb1 + 4096); cp16(gb2 + 32, lb2 + 4096);
    ga1 += 64; ga2 += 64; gb1 += 64; gb2 += 64;
    __syncthreads();

#pragma unroll
    for (int h = 0; h < 2; ++h) {
      const unsigned short* bA = &sA[h << 12];
      const unsigned short* bB = &sB[h << 12];
      bf16x8 af[4], bfr[4];
#pragma unroll
      for (int i = 0; i < 4; ++i)
        af[i] = *(const bf16x8*)&bA[((am + (i << 4)) << 5) + fq];
#pragma unroll
      for (int j = 0; j < 4; ++j)
        bfr[j] = *(const bf16x8*)&bB[((bn + (j << 4)) << 5) + fq];
#pragma unroll
      for (int i = 0; i < 4; ++i)
#pragma unroll
        for (int j = 0; j < 4; ++j)
          acc[i][j] = __builtin_amdgcn_mfma_f32_16x16x32_bf16(af[i], bfr[j], acc[i][j], 0, 0, 0);
    }
  }

  const int cr = (lane >> 4) << 2;
  const int ccol = lane & 15;
#pragma unroll
  for (int j = 0; j < 4; ++j) {
    const long col = col0 + wc + (j << 4) + ccol;
    if (col < Nout) {
      const float bvc = bias ? bias[col] : 0.f;
#pragma unroll
      for (int i = 0; i < 4; ++i) {
        const long rowb = row0 + wr + (i << 4) + cr;
#pragma unroll
        for (int r = 0; r < 4; ++r) {
          float v = acc[i][j][r] * alpha + bvc;
          const long idx = (rowb + r) * (long)Nout + col;
          if (OBF16)
            ((unsigned short*)Cout)[idx] = f2bf(v);
          else
            ((float*)Cout)[idx] = v;
        }
      }
    }
  }
}

// ---------------------------------------------------------------------------
// x -> (bf16, fp8) in one pass (x read once instead of twice)
__global__ __launch_bounds__(256) void cast_x_dual(
    const float* __restrict__ in, unsigned short* __restrict__ ob,
    unsigned char* __restrict__ o8, int n) {
  int i = (blockIdx.x * 256 + threadIdx.x) * 4;
  if (i + 3 < n) {
    float4 v = *(const float4*)(in + i);
    ushort4 o;
    o.x = f2bf(v.x); o.y = f2bf(v.y); o.z = f2bf(v.z); o.w = f2bf(v.w);
    *(ushort4*)(ob + i) = o;
    int p = __builtin_amdgcn_cvt_pk_fp8_f32(v.x, v.y, 0, false);
    p = __builtin_amdgcn_cvt_pk_fp8_f32(v.z, v.w, p, true);
    *(int*)(o8 + i) = p;
  }
}

__global__ __launch_bounds__(256) void zero_f32(float* __restrict__ p, int n) {
  int i = blockIdx.x * 256 + threadIdx.x;
  if (i < n) p[i] = 0.f;
}

__global__ __launch_bounds__(256) void cat_bias2(
    const float* __restrict__ a, const float* __restrict__ b,
    float* __restrict__ o) {
  int i = blockIdx.x * 256 + threadIdx.x;
  if (i < 1024) o[i] = a[i];
  else if (i < 2048) o[i] = b[i - 1024];
}

__global__ __launch_bounds__(1) void sentinel_kernel(float* __restrict__ out) {
  out[0] = -12345.0f;
}

// in[R][C] fp32 -> out[Cpad][R] bf16, rows C..Cpad-1 zeroed. block (32,8)
__global__ void transpose_f32_to_bf16(const float* __restrict__ in,
                                      unsigned short* __restrict__ out,
                                      int R, int C, int Cpad) {
  __shared__ float tile[32][33];
  int c0 = blockIdx.x * 32, r0 = blockIdx.y * 32;
  int tx = threadIdx.x, ty = threadIdx.y;
  for (int i = ty; i < 32; i += 8) {
    int r = r0 + i, c = c0 + tx;
    tile[i][tx] = (r < R && c < C) ? in[(size_t)r * C + c] : 0.f;
  }
  __syncthreads();
  for (int i = ty; i < 32; i += 8) {
    int oc = c0 + i, orr = r0 + tx;
    if (oc < Cpad && orr < R) out[(size_t)oc * R + orr] = f2bf(tile[tx][i]);
  }
}

// in[R][C] fp32 -> out[C][R] fp8. R,C multiples of 32. block (32,8)
__global__ void transpose_f32_to_fp8(const float* __restrict__ in,
                                     unsigned char* __restrict__ out,
                                     int R, int C) {
  __shared__ float tile[32][33];
  int c0 = blockIdx.x * 32, r0 = blockIdx.y * 32;
  int tx = threadIdx.x, ty = threadIdx.y;
  for (int i = ty; i < 32; i += 8)
    tile[i][tx] = in[(size_t)(r0 + i) * C + (c0 + tx)];
  __syncthreads();
  for (int i = ty; i < 32; i += 8)
    out[(size_t)(c0 + i) * R + (r0 + tx)] = f2fp8(tile[tx][i]);
}

// beta = sigmoid(inv_l*sum(av*(Wb0+Wb2)) + sum(xr*(Wb1-Wb2)) + bb)
// u = beta*xr + (1-beta)*av*inv_l   (bf16 out). xr bf16, av fp32, both ld 1024.
__global__ __launch_bounds__(256) void beta_combine(
    const unsigned short* __restrict__ xr, const float* __restrict__ av,
    const float* __restrict__ l, const float* __restrict__ Wb,
    const float* __restrict__ bb, unsigned short* __restrict__ u) {
  const int row = blockIdx.x;
  const int tid = threadIdx.x;
  const unsigned short* xp = xr + (size_t)row * Dd;
  const float* ap = av + (size_t)row * Dd;
  const float invl = 1.f / l[row];
  __shared__ float red[8];
  float sa, sx;
  const int j = tid * 4;
  float4 a4 = *(const float4*)(ap + j);
  ushort4 x4 = *(const ushort4*)(xp + j);
  {
    float4 w0 = *(const float4*)(Wb + j);
    float4 w1 = *(const float4*)(Wb + Dd + j);
    float4 w2 = *(const float4*)(Wb + 2 * Dd + j);
    sa = a4.x * (w0.x + w2.x) + a4.y * (w0.y + w2.y) +
         a4.z * (w0.z + w2.z) + a4.w * (w0.w + w2.w);
    sx = bf2f(x4.x) * (w1.x - w2.x) + bf2f(x4.y) * (w1.y - w2.y) +
         bf2f(x4.z) * (w1.z - w2.z) + bf2f(x4.w) * (w1.w - w2.w);
  }
  sa = wred_sum(sa);
  sx = wred_sum(sx);
  if ((tid & 63) == 0) {
    red[tid >> 6] = sa;
    red[4 + (tid >> 6)] = sx;
  }
  __syncthreads();
  const float s = (red[0] + red[1] + red[2] + red[3]) * invl +
                  (red[4] + red[5] + red[6] + red[7]) + bb[0];
  const float beta = 1.f / (1.f + __expf(-s));
  unsigned short* up = u + (size_t)row * Dd;
  ushort4 o;
  o.x = f2bf(beta * bf2f(x4.x) + (1.f - beta) * a4.x * invl);
  o.y = f2bf(beta * bf2f(x4.y) + (1.f - beta) * a4.y * invl);
  o.z = f2bf(beta * bf2f(x4.z) + (1.f - beta) * a4.z * invl);
  o.w = f2bf(beta * bf2f(x4.w) + (1.f - beta) * a4.w * invl);
  *(ushort4*)(up + j) = o;
}

// ---------------------------------------------------------------------------
extern "C" void kernel_launch(void* const* d_in, const int* in_sizes, int n_in,
                              void* d_out, int out_size, void* d_ws, size_t ws_size,
                              hipStream_t stream) {
  (void)in_sizes; (void)n_in; (void)out_size;
  const float* x      = (const float*)d_in[0];
  const float* W_skip = (const float*)d_in[1];
  const float* b_skip = (const float*)d_in[2];
  const float* W_q    = (const float*)d_in[3];
  const float* b_q    = (const float*)d_in[4];
  const float* W_k    = (const float*)d_in[5];
  const float* b_k    = (const float*)d_in[6];
  const float* W_v    = (const float*)d_in[7];
  const float* b_v    = (const float*)d_in[8];
  const float* W_beta = (const float*)d_in[9];
  const float* b_beta = (const float*)d_in[10];
  const float* W_fc   = (const float*)d_in[11];
  const float* b_fc   = (const float*)d_in[12];
  float* out = (float*)d_out;

  char* w = (char*)d_ws;
  size_t off = 0;
  auto take = [&](size_t b) -> void* {
    void* p = w + off;
    off += (b + 255) & ~(size_t)255;
    return p;
  };
  const size_t szND2 = (size_t)Nn * Dd * 2;
  unsigned short* xb   = (unsigned short*)take(szND2);            // x bf16 (-> ub)
  unsigned char*  xf8  = (unsigned char*)take((size_t)Nn * Dd);   // x fp8
  unsigned char*  qkf  = (unsigned char*)take((size_t)Nn * 2048); // [q|k] fp8
  unsigned short* xrb  = (unsigned short*)take(szND2);            // x_r bf16
  unsigned char*  vtf  = (unsigned char*)take((size_t)Dd * Nn);   // v^T fp8 [D][N]
  float*          avf  = (float*)take((size_t)Nn * Dd * 4);       // unnorm P@V fp32
  unsigned char*  wqkt = (unsigned char*)take((size_t)2048 * Dd); // [Wq|Wk]^T fp8
  unsigned char*  wvt8 = (unsigned char*)take((size_t)Dd * Dd);   // Wv^T fp8
  unsigned short* wst  = (unsigned short*)take((size_t)Dd * Dd * 2);
  unsigned short* wft  = (unsigned short*)take((size_t)Dd * Dd * 2);  // 1000->1024
  unsigned char*  Sc   = (unsigned char*)take((size_t)Nn * Nn);   // P fp8 [N][N]
  float*          lsum = (float*)take((size_t)Nn * 4);
  float*          bqk  = (float*)take(2048 * 4);
  unsigned short* ub   = xb;                                      // overlay

  if (off > ws_size) {  // workspace too small -> unmistakable sentinel
    sentinel_kernel<<<1, 1, 0, stream>>>(out);
    return;
  }

  dim3 tb(32, 8);
  cast_x_dual<<<Nn * Dd / 1024, 256, 0, stream>>>(x, xb, xf8, Nn * Dd);
  transpose_f32_to_fp8<<<dim3(32, 32), tb, 0, stream>>>(W_q, wqkt, Dd, Dd);
  transpose_f32_to_fp8<<<dim3(32, 32), tb, 0, stream>>>(W_k, wqkt + (size_t)Dd * Dd, Dd, Dd);
  transpose_f32_to_fp8<<<dim3(32, 32), tb, 0, stream>>>(W_v, wvt8, Dd, Dd);
  transpose_f32_to_bf16<<<dim3(32, 32), tb, 0, stream>>>(W_skip, wst, Dd, Dd, Dd);
  transpose_f32_to_bf16<<<dim3(32, 32), tb, 0, stream>>>(W_fc, wft, Dd, Cc_, 1024);
  cat_bias2<<<8, 256, 0, stream>>>(b_q, b_k, bqk);
  zero_f32<<<Nn / 256, 256, 0, stream>>>(lsum, Nn);
  zero_f32<<<Nn * Dd / 256, 256, 0, stream>>>(avf, Nn * Dd);

  // [q|k] = x @ [Wq|Wk] + bias   (fp8 in/out): [8192][2048]
  gemm_mx8<1><<<dim3(32, 8, 1), 512, 0, stream>>>(
      xf8, wqkt, bqk, qkf, Dd, 2048, Dd, Dd, 1.f, nullptr);
  // v^T = Wv^T @ x^T + b_v (bias per row): [1024][8192] fp8 (old 128^2 kernel)
  gemm_mx<1, 0, 1><<<dim3(8, 64), 256, 0, stream>>>(
      wvt8, xf8, b_v, vtf, Dd, Nn, Dd, Dd, 1.f, nullptr);
  // x_r = x @ W_skip + b_skip  (bf16): [8192][1024]
  gemm_bt<1><<<dim3(64, 8), 256, 0, stream>>>(
      xb, wst, b_skip, xrb, Dd, Dd, Dd, Dd, 1.f);

  // P = exp(q @ k^T / 32)  (fp8 out, fused row-sums; no-max softmax is safe:
  // |scores/32| <~ 3 -> exp in [0.05, 30], well within e4m3 range)
  gemm_mx8<2><<<dim3(32, 32, 1), 512, 0, stream>>>(
      qkf, qkf + 1024, nullptr, Sc, Dd, Nn, 2048, 2048, 0.03125f, lsum);
  // av = P @ v  (fp32 atomic-accumulate, split-K=2 so grid fills all 256 CUs):
  // [8192][1024], each z does K=4096
  gemm_mx8<0><<<dim3(32, 4, 2), 512, 0, stream>>>(
      Sc, vtf, nullptr, avf, 4096, Dd, Nn, Nn, 1.f, nullptr);

  beta_combine<<<Nn, 256, 0, stream>>>(xrb, avf, lsum, W_beta, b_beta, ub);

  gemm_bt<0><<<dim3(64, 8), 256, 0, stream>>>(
      ub, wft, b_fc, out, Dd, Cc_, Dd, Dd, 1.f);
}

// Round 3
// 404.270 us; speedup vs baseline: 1.1230x; 1.1230x over previous
//
#include <hip/hip_runtime.h>
#include <stdint.h>

#define Nn 8192
#define Dd 1024
#define Cc_ 1000

typedef __bf16 bf16x8 __attribute__((ext_vector_type(8)));
typedef float f32x4 __attribute__((ext_vector_type(4)));
typedef int i32x4 __attribute__((ext_vector_type(4)));
typedef int i32x8 __attribute__((ext_vector_type(8)));
typedef const __attribute__((address_space(1))) void* gas1_t;
typedef __attribute__((address_space(3))) void* las3_t;

__device__ __forceinline__ unsigned short f2bf(float f) {
  unsigned u = __float_as_uint(f);
  u = (u + 0x7fffu + ((u >> 16) & 1u)) >> 16;  // RNE
  return (unsigned short)u;
}
__device__ __forceinline__ float bf2f(unsigned short h) {
  return __uint_as_float(((unsigned)h) << 16);
}
__device__ __forceinline__ unsigned char f2fp8(float v) {
  int p = __builtin_amdgcn_cvt_pk_fp8_f32(v, v, 0, false);  // OCP e4m3 on gfx950
  return (unsigned char)(p & 0xff);
}
__device__ __forceinline__ void cp16(const void* g, void* l) {
  __builtin_amdgcn_global_load_lds((gas1_t)g, (las3_t)l, 16, 0, 0);
}
__device__ __forceinline__ float wred_sum(float v) {
#pragma unroll
  for (int m = 32; m; m >>= 1) v += __shfl_xor(v, m, 64);
  return v;
}

// ---------------------------------------------------------------------------
// MX-fp8 GEMM: C = alpha*(A[M][K] @ Bt[*][K]^T) (+bias) (exp+rowsum)
// mfma_scale_f32_16x16x128_f8f6f4, unit scales (0x7F e8m0 = 1.0).
// BK=128. 128x128 tile, 4 waves, 2-phase loop (3 resident blocks/CU gives
// cross-block MFMA/LDS overlap -- measured better than an 8-wave 4-phase
// pipelined variant, round 2).
//
// LDS layout: each 128-B logical row r stored as two 64-B half-rows with
// 16-B units swizzled (verified bijection staging<->frag-read).
// ROUND-3 CONFLICT FIX: the original swizzle used only r&7; frag-read lanes
// (m,q) and (m+8,q) had identical byte%128 at rows 1024 B apart -> same
// banks (SQ_LDS_BANK_CONFLICT 8.4M/dispatch, ~+4 cyc per ds_read_b128).
// Fix: XOR address bit 4 with row bit 3 on BOTH sides:
//   staging: go ^= (c&1)<<4   (row bit3 of chunk c's rows == c&1)
//   frag read: aoff ^= ((m>>3)&1)<<4  (row bit3 == m bit3; hi stays lo^16 --
//   for bit3 rows the two 16-B units swap slots and base^16 reads them in
//   correct unit order; verified algebraically both directions)
// Staging stays wave-contiguous lane*16 for global_load_lds (wave-uniform
// LDS dest per m104/m108).
// Grid (M/128, ceil(Nout/128)); K%128==0; Bt needs ceil128(Nout) valid rows.
// ---------------------------------------------------------------------------
template <int OFP8, int ER, int BROW>
__global__ __launch_bounds__(256, 3) void gemm_mx(
    const unsigned char* __restrict__ A,
    const unsigned char* __restrict__ Bt,
    const float* __restrict__ bias,
    void* __restrict__ Cout,
    int K, int Nout, int lda, int ldb, float alpha,
    float* __restrict__ lsum) {
  __shared__ __attribute__((aligned(16))) unsigned char sA[16384];
  __shared__ __attribute__((aligned(16))) unsigned char sB[16384];

  const int tid = threadIdx.x;
  const int lane = tid & 63;
  const int wave = tid >> 6;
  const int wr = (wave >> 1) << 6;
  const int wc = (wave & 1) << 6;
  const long row0 = (long)blockIdx.x << 7;
  const long col0 = (long)blockIdx.y << 7;

  // staging: chunk c = wave*4+s covers LDS bytes [c*1024,c*1024+1024) =
  // 8 logical rows r = 8c + (lane>>3). Row bit3 == s&1 -> conflict-fix XOR.
  const unsigned char* gA[4];
  const unsigned char* gB[4];
  unsigned char* lA[4];
  unsigned char* lB[4];
  {
    const int r_ = (lane >> 3);
    const int go = ((((lane >> 2) ^ (lane >> 3)) & 1) << 6) +
                   (((lane & 3) ^ ((lane >> 4) & 3)) << 4);
#pragma unroll
    for (int s = 0; s < 4; ++s) {
      const int c = (wave << 2) + s;
      const int gos = go ^ ((s & 1) << 4);  // round-3 conflict fix
      gA[s] = A + (row0 + (c << 3) + r_) * (long)lda + gos;
      gB[s] = Bt + (col0 + (c << 3) + r_) * (long)ldb + gos;
      lA[s] = &sA[c << 10];
      lB[s] = &sB[c << 10];
    }
  }

  f32x4 acc[4][4] = {};

  // frag read: lane (m,q) reads logical row r=w+m+16i; row bit3 = m bit3.
  const int m_ = lane & 15;
  const int q_ = lane >> 4;
  const int fix = ((m_ >> 3) & 1) << 4;  // round-3 conflict fix
  const int aoffA = ((wr + m_) << 7) +
                    (((((q_ >> 1) ^ m_) & 1) << 6) +
                     (((((q_ & 1) << 1) ^ ((m_ >> 1) & 3))) << 4) ^ fix);
  const int aoffB = ((wc + m_) << 7) +
                    (((((q_ >> 1) ^ m_) & 1) << 6) +
                     (((((q_ & 1) << 1) ^ ((m_ >> 1) & 3))) << 4) ^ fix);

  for (int k0 = 0; k0 < K; k0 += 128) {
    __syncthreads();  // prior iter's LDS reads done
#pragma unroll
    for (int s = 0; s < 4; ++s) {
      cp16(gA[s], lA[s]);
      cp16(gB[s], lB[s]);
      gA[s] += 128;
      gB[s] += 128;
    }
    __syncthreads();  // staging visible

    i32x8 af[4], bfr[4];
#pragma unroll
    for (int i = 0; i < 4; ++i) {
      const int ba = aoffA + (i << 11);
      i32x4 lo = *(const i32x4*)&sA[ba];
      i32x4 hi = *(const i32x4*)&sA[ba ^ 16];
      af[i] = __builtin_shufflevector(lo, hi, 0, 1, 2, 3, 4, 5, 6, 7);
    }
#pragma unroll
    for (int j = 0; j < 4; ++j) {
      const int bb = aoffB + (j << 11);
      i32x4 lo = *(const i32x4*)&sB[bb];
      i32x4 hi = *(const i32x4*)&sB[bb ^ 16];
      bfr[j] = __builtin_shufflevector(lo, hi, 0, 1, 2, 3, 4, 5, 6, 7);
    }
#pragma unroll
    for (int i = 0; i < 4; ++i)
#pragma unroll
      for (int j = 0; j < 4; ++j)
        acc[i][j] = __builtin_amdgcn_mfma_scale_f32_16x16x128_f8f6f4(
            af[i], bfr[j], acc[i][j], 0, 0, 0, 0x7f7f7f7f, 0, 0x7f7f7f7f);
  }

  // C/D layout: col = lane&15, row = (lane>>4)*4 + reg   [m89-verified]
  const int cr = (lane >> 4) << 2;
  const int ccol = lane & 15;
  if (ER) {
    // exp + fp8 store + fused row-sum (full tiles only)
    float rs[4][4];
#pragma unroll
    for (int i = 0; i < 4; ++i)
#pragma unroll
      for (int r = 0; r < 4; ++r) rs[i][r] = 0.f;
#pragma unroll
    for (int j = 0; j < 4; ++j) {
      const long col = col0 + wc + (j << 4) + ccol;
#pragma unroll
      for (int i = 0; i < 4; ++i) {
        const long rowb = row0 + wr + (i << 4) + cr;
#pragma unroll
        for (int r = 0; r < 4; ++r) {
          float v = __expf(acc[i][j][r] * alpha);
          rs[i][r] += v;
          ((unsigned char*)Cout)[(rowb + r) * (long)Nout + col] = f2fp8(v);
        }
      }
    }
#pragma unroll
    for (int i = 0; i < 4; ++i)
#pragma unroll
      for (int r = 0; r < 4; ++r) {
        float s = rs[i][r];
#pragma unroll
        for (int m = 1; m < 16; m <<= 1) s += __shfl_xor(s, m, 64);
        if (ccol == 0)
          atomicAdd(&lsum[row0 + wr + (i << 4) + cr + r], s);
      }
  } else {
#pragma unroll
    for (int j = 0; j < 4; ++j) {
      const long col = col0 + wc + (j << 4) + ccol;
      if (col < Nout) {
        float bvc = 0.f;
        if (!BROW && bias) bvc = bias[col];
#pragma unroll
        for (int i = 0; i < 4; ++i) {
          const long rowb = row0 + wr + (i << 4) + cr;
#pragma unroll
          for (int r = 0; r < 4; ++r) {
            float v = acc[i][j][r] * alpha + bvc;
            if (BROW) v += bias[rowb + r];
            const long idx = (rowb + r) * (long)Nout + col;
            if (OFP8)
              ((unsigned char*)Cout)[idx] = f2fp8(v);
            else
              ((float*)Cout)[idx] = v;
          }
        }
      }
    }
  }
}

// ---------------------------------------------------------------------------
// bf16 GEMM (x_r projection and final FC): round-3's verified kernel.
// ---------------------------------------------------------------------------
template <int OBF16>
__global__ __launch_bounds__(256, 4) void gemm_bt(
    const unsigned short* __restrict__ A,
    const unsigned short* __restrict__ Bt,
    const float* __restrict__ bias,
    void* __restrict__ Cout,
    int K, int Nout, int lda, int ldb, float alpha) {
  __shared__ __attribute__((aligned(16))) unsigned short sA[8192];
  __shared__ __attribute__((aligned(16))) unsigned short sB[8192];

  const int tid = threadIdx.x;
  const int lane = tid & 63;
  const int wave = tid >> 6;
  const int wr = (wave >> 1) << 6;
  const int wc = (wave & 1) << 6;
  const long row0 = (long)blockIdx.x << 7;
  const long col0 = (long)blockIdx.y << 7;

  const int srow = (wave << 4) + (lane >> 2);
  const int sq = (lane & 3) ^ ((lane >> 3) & 3);
  const unsigned short* ga1 = A + (row0 + srow) * lda + sq * 8;
  const unsigned short* ga2 = ga1 + (long)64 * lda;
  const unsigned short* gb1 = Bt + (col0 + srow) * ldb + sq * 8;
  const unsigned short* gb2 = gb1 + (long)64 * ldb;
  unsigned short* la1 = &sA[wave * 512];
  unsigned short* la2 = &sA[2048 + wave * 512];
  unsigned short* lb1 = &sB[wave * 512];
  unsigned short* lb2 = &sB[2048 + wave * 512];

  f32x4 acc[4][4] = {};

  const int fq = ((lane >> 4) ^ ((lane >> 1) & 3)) << 3;
  const int am = wr + (lane & 15);
  const int bn = wc + (lane & 15);

  for (int k0 = 0; k0 < K; k0 += 64) {
    __syncthreads();
    cp16(ga1, la1);             cp16(ga2, la2);
    cp16(ga1 + 32, la1 + 4096); cp16(ga2 + 32, la2 + 4096);
    cp16(gb1, lb1);             cp16(gb2, lb2);
    cp16(gb1 + 32, lb1 + 4096); cp16(gb2 + 32, lb2 + 4096);
    ga1 += 64; ga2 += 64; gb1 += 64; gb2 += 64;
    __syncthreads();

#pragma unroll
    for (int h = 0; h < 2; ++h) {
      const unsigned short* bA = &sA[h << 12];
      const unsigned short* bB = &sB[h << 12];
      bf16x8 af[4], bfr[4];
#pragma unroll
      for (int i = 0; i < 4; ++i)
        af[i] = *(const bf16x8*)&bA[((am + (i << 4)) << 5) + fq];
#pragma unroll
      for (int j = 0; j < 4; ++j)
        bfr[j] = *(const bf16x8*)&bB[((bn + (j << 4)) << 5) + fq];
#pragma unroll
      for (int i = 0; i < 4; ++i)
#pragma unroll
        for (int j = 0; j < 4; ++j)
          acc[i][j] = __builtin_amdgcn_mfma_f32_16x16x32_bf16(af[i], bfr[j], acc[i][j], 0, 0, 0);
    }
  }

  const int cr = (lane >> 4) << 2;
  const int ccol = lane & 15;
#pragma unroll
  for (int j = 0; j < 4; ++j) {
    const long col = col0 + wc + (j << 4) + ccol;
    if (col < Nout) {
      const float bvc = bias ? bias[col] : 0.f;
#pragma unroll
      for (int i = 0; i < 4; ++i) {
        const long rowb = row0 + wr + (i << 4) + cr;
#pragma unroll
        for (int r = 0; r < 4; ++r) {
          float v = acc[i][j][r] * alpha + bvc;
          const long idx = (rowb + r) * (long)Nout + col;
          if (OBF16)
            ((unsigned short*)Cout)[idx] = f2bf(v);
          else
            ((float*)Cout)[idx] = v;
        }
      }
    }
  }
}

// ---------------------------------------------------------------------------
// x -> (bf16, fp8) in one pass (x read once instead of twice)
__global__ __launch_bounds__(256) void cast_x_dual(
    const float* __restrict__ in, unsigned short* __restrict__ ob,
    unsigned char* __restrict__ o8, int n) {
  int i = (blockIdx.x * 256 + threadIdx.x) * 4;
  if (i + 3 < n) {
    float4 v = *(const float4*)(in + i);
    ushort4 o;
    o.x = f2bf(v.x); o.y = f2bf(v.y); o.z = f2bf(v.z); o.w = f2bf(v.w);
    *(ushort4*)(ob + i) = o;
    int p = __builtin_amdgcn_cvt_pk_fp8_f32(v.x, v.y, 0, false);
    p = __builtin_amdgcn_cvt_pk_fp8_f32(v.z, v.w, p, true);
    *(int*)(o8 + i) = p;
  }
}

__global__ __launch_bounds__(256) void zero_f32(float* __restrict__ p, int n) {
  int i = blockIdx.x * 256 + threadIdx.x;
  if (i < n) p[i] = 0.f;
}

__global__ __launch_bounds__(256) void cat_bias2(
    const float* __restrict__ a, const float* __restrict__ b,
    float* __restrict__ o) {
  int i = blockIdx.x * 256 + threadIdx.x;
  if (i < 1024) o[i] = a[i];
  else if (i < 2048) o[i] = b[i - 1024];
}

__global__ __launch_bounds__(1) void sentinel_kernel(float* __restrict__ out) {
  out[0] = -12345.0f;
}

// in[R][C] fp32 -> out[Cpad][R] bf16, rows C..Cpad-1 zeroed. block (32,8)
__global__ void transpose_f32_to_bf16(const float* __restrict__ in,
                                      unsigned short* __restrict__ out,
                                      int R, int C, int Cpad) {
  __shared__ float tile[32][33];
  int c0 = blockIdx.x * 32, r0 = blockIdx.y * 32;
  int tx = threadIdx.x, ty = threadIdx.y;
  for (int i = ty; i < 32; i += 8) {
    int r = r0 + i, c = c0 + tx;
    tile[i][tx] = (r < R && c < C) ? in[(size_t)r * C + c] : 0.f;
  }
  __syncthreads();
  for (int i = ty; i < 32; i += 8) {
    int oc = c0 + i, orr = r0 + tx;
    if (oc < Cpad && orr < R) out[(size_t)oc * R + orr] = f2bf(tile[tx][i]);
  }
}

// in[R][C] fp32 -> out[C][R] fp8. R,C multiples of 32. block (32,8)
__global__ void transpose_f32_to_fp8(const float* __restrict__ in,
                                     unsigned char* __restrict__ out,
                                     int R, int C) {
  __shared__ float tile[32][33];
  int c0 = blockIdx.x * 32, r0 = blockIdx.y * 32;
  int tx = threadIdx.x, ty = threadIdx.y;
  for (int i = ty; i < 32; i += 8)
    tile[i][tx] = in[(size_t)(r0 + i) * C + (c0 + tx)];
  __syncthreads();
  for (int i = ty; i < 32; i += 8)
    out[(size_t)(c0 + i) * R + (r0 + tx)] = f2fp8(tile[tx][i]);
}

// beta = sigmoid(inv_l*sum(av*(Wb0+Wb2)) + sum(xr*(Wb1-Wb2)) + bb)
// u = beta*xr + (1-beta)*av*inv_l   (bf16 out). xr bf16, av fp32, both ld 1024.
__global__ __launch_bounds__(256) void beta_combine(
    const unsigned short* __restrict__ xr, const float* __restrict__ av,
    const float* __restrict__ l, const float* __restrict__ Wb,
    const float* __restrict__ bb, unsigned short* __restrict__ u) {
  const int row = blockIdx.x;
  const int tid = threadIdx.x;
  const unsigned short* xp = xr + (size_t)row * Dd;
  const float* ap = av + (size_t)row * Dd;
  const float invl = 1.f / l[row];
  __shared__ float red[8];
  float sa, sx;
  const int j = tid * 4;
  float4 a4 = *(const float4*)(ap + j);
  ushort4 x4 = *(const ushort4*)(xp + j);
  {
    float4 w0 = *(const float4*)(Wb + j);
    float4 w1 = *(const float4*)(Wb + Dd + j);
    float4 w2 = *(const float4*)(Wb + 2 * Dd + j);
    sa = a4.x * (w0.x + w2.x) + a4.y * (w0.y + w2.y) +
         a4.z * (w0.z + w2.z) + a4.w * (w0.w + w2.w);
    sx = bf2f(x4.x) * (w1.x - w2.x) + bf2f(x4.y) * (w1.y - w2.y) +
         bf2f(x4.z) * (w1.z - w2.z) + bf2f(x4.w) * (w1.w - w2.w);
  }
  sa = wred_sum(sa);
  sx = wred_sum(sx);
  if ((tid & 63) == 0) {
    red[tid >> 6] = sa;
    red[4 + (tid >> 6)] = sx;
  }
  __syncthreads();
  const float s = (red[0] + red[1] + red[2] + red[3]) * invl +
                  (red[4] + red[5] + red[6] + red[7]) + bb[0];
  const float beta = 1.f / (1.f + __expf(-s));
  unsigned short* up = u + (size_t)row * Dd;
  ushort4 o;
  o.x = f2bf(beta * bf2f(x4.x) + (1.f - beta) * a4.x * invl);
  o.y = f2bf(beta * bf2f(x4.y) + (1.f - beta) * a4.y * invl);
  o.z = f2bf(beta * bf2f(x4.z) + (1.f - beta) * a4.z * invl);
  o.w = f2bf(beta * bf2f(x4.w) + (1.f - beta) * a4.w * invl);
  *(ushort4*)(up + j) = o;
}

// ---------------------------------------------------------------------------
extern "C" void kernel_launch(void* const* d_in, const int* in_sizes, int n_in,
                              void* d_out, int out_size, void* d_ws, size_t ws_size,
                              hipStream_t stream) {
  (void)in_sizes; (void)n_in; (void)out_size;
  const float* x      = (const float*)d_in[0];
  const float* W_skip = (const float*)d_in[1];
  const float* b_skip = (const float*)d_in[2];
  const float* W_q    = (const float*)d_in[3];
  const float* b_q    = (const float*)d_in[4];
  const float* W_k    = (const float*)d_in[5];
  const float* b_k    = (const float*)d_in[6];
  const float* W_v    = (const float*)d_in[7];
  const float* b_v    = (const float*)d_in[8];
  const float* W_beta = (const float*)d_in[9];
  const float* b_beta = (const float*)d_in[10];
  const float* W_fc   = (const float*)d_in[11];
  const float* b_fc   = (const float*)d_in[12];
  float* out = (float*)d_out;

  char* w = (char*)d_ws;
  size_t off = 0;
  auto take = [&](size_t b) -> void* {
    void* p = w + off;
    off += (b + 255) & ~(size_t)255;
    return p;
  };
  const size_t szND2 = (size_t)Nn * Dd * 2;
  unsigned short* xb   = (unsigned short*)take(szND2);            // x bf16 (-> ub)
  unsigned char*  xf8  = (unsigned char*)take((size_t)Nn * Dd);   // x fp8
  unsigned char*  qkf  = (unsigned char*)take((size_t)Nn * 2048); // [q|k] fp8
  unsigned short* xrb  = (unsigned short*)take(szND2);            // x_r bf16
  unsigned char*  vtf  = (unsigned char*)take((size_t)Dd * Nn);   // v^T fp8 [D][N]
  float*          avf  = (float*)take((size_t)Nn * Dd * 4);       // unnorm P@V fp32
  unsigned char*  wqkt = (unsigned char*)take((size_t)2048 * Dd); // [Wq|Wk]^T fp8
  unsigned char*  wvt8 = (unsigned char*)take((size_t)Dd * Dd);   // Wv^T fp8
  unsigned short* wst  = (unsigned short*)take((size_t)Dd * Dd * 2);
  unsigned short* wft  = (unsigned short*)take((size_t)Dd * Dd * 2);  // 1000->1024
  unsigned char*  Sc   = (unsigned char*)take((size_t)Nn * Nn);   // P fp8 [N][N]
  float*          lsum = (float*)take((size_t)Nn * 4);
  float*          bqk  = (float*)take(2048 * 4);
  unsigned short* ub   = xb;                                      // overlay

  if (off > ws_size) {  // workspace too small -> unmistakable sentinel
    sentinel_kernel<<<1, 1, 0, stream>>>(out);
    return;
  }

  dim3 tb(32, 8);
  cast_x_dual<<<Nn * Dd / 1024, 256, 0, stream>>>(x, xb, xf8, Nn * Dd);
  transpose_f32_to_fp8<<<dim3(32, 32), tb, 0, stream>>>(W_q, wqkt, Dd, Dd);
  transpose_f32_to_fp8<<<dim3(32, 32), tb, 0, stream>>>(W_k, wqkt + (size_t)Dd * Dd, Dd, Dd);
  transpose_f32_to_fp8<<<dim3(32, 32), tb, 0, stream>>>(W_v, wvt8, Dd, Dd);
  transpose_f32_to_bf16<<<dim3(32, 32), tb, 0, stream>>>(W_skip, wst, Dd, Dd, Dd);
  transpose_f32_to_bf16<<<dim3(32, 32), tb, 0, stream>>>(W_fc, wft, Dd, Cc_, 1024);
  cat_bias2<<<8, 256, 0, stream>>>(b_q, b_k, bqk);
  zero_f32<<<Nn / 256, 256, 0, stream>>>(lsum, Nn);

  // [q|k] = x @ [Wq|Wk] + bias   (fp8 in/out): [8192][2048]
  gemm_mx<1, 0, 0><<<dim3(64, 16), 256, 0, stream>>>(
      xf8, wqkt, bqk, qkf, Dd, 2048, Dd, Dd, 1.f, nullptr);
  // v^T = Wv^T @ x^T + b_v (bias per row): [1024][8192] fp8
  gemm_mx<1, 0, 1><<<dim3(8, 64), 256, 0, stream>>>(
      wvt8, xf8, b_v, vtf, Dd, Nn, Dd, Dd, 1.f, nullptr);
  // x_r = x @ W_skip + b_skip  (bf16): [8192][1024]
  gemm_bt<1><<<dim3(64, 8), 256, 0, stream>>>(
      xb, wst, b_skip, xrb, Dd, Dd, Dd, Dd, 1.f);

  // P = exp(q @ k^T / 32)  (fp8 out, fused row-sums; no-max softmax is safe:
  // |scores/32| <~ 3 -> exp in [0.05, 30], well within e4m3 range)
  gemm_mx<1, 1, 0><<<dim3(64, 64), 256, 0, stream>>>(
      qkf, qkf + 1024, nullptr, Sc, Dd, Nn, 2048, 2048, 0.03125f, lsum);
  // av = P @ v  (fp32 out): [8192][1024], K=8192
  gemm_mx<0, 0, 0><<<dim3(64, 8), 256, 0, stream>>>(
      Sc, vtf, nullptr, avf, Nn, Dd, Nn, Nn, 1.f, nullptr);

  beta_combine<<<Nn, 256, 0, stream>>>(xrb, avf, lsum, W_beta, b_beta, ub);

  gemm_bt<0><<<dim3(64, 8), 256, 0, stream>>>(
      ub, wft, b_fc, out, Dd, Cc_, Dd, Dd, 1.f);
}